// Round 3
// baseline (57.896 us; speedup 1.0000x reference)
//
#include <hip/hip_runtime.h>

#define THREADS 256
#define RB      16     // rows per block
#define LCAP    128    // candidate-list capacity
#define KF      80     // compiled K (harness K=80)
#define K2      160    // 2*KF (C|D)
#define NPART   8      // XCD-aligned partition count

__device__ __forceinline__ unsigned fmap(float x) {   // order-preserving float->uint
  unsigned u = __float_as_uint(x);
  return (u >> 31) ? ~u : (u | 0x80000000u);
}

__global__ __launch_bounds__(THREADS, 2)
void mainK(const float* __restrict__ S, const float* __restrict__ J,
           const float* __restrict__ C, const float* __restrict__ D,
           float tau,
           float* __restrict__ slotPart, int* __restrict__ slotCount,
           int* __restrict__ subctr, int* __restrict__ master, int* __restrict__ gen,
           int* __restrict__ leader,
           float* __restrict__ out, int N, int K) {
  __shared__ int   listIdx[LCAP];
  __shared__ float listVal[LCAP];
  __shared__ int   cnts[THREADS];
  __shared__ unsigned long long rowKey[RB];
  __shared__ int   rowSlot[RB];
  __shared__ int   rowLocal[RB];
  __shared__ int   touchSlot[RB];
  __shared__ int   touchCnt[RB];
  __shared__ float invCnt[RB];
  __shared__ int   unresR[RB];
  __shared__ int   sT, sNT, sNU;
  __shared__ unsigned long long bkey;
  __shared__ float slab[RB * K2];          // 10.2 KB

  const int tid = threadIdx.x;
  const int b   = blockIdx.x;
  const int i0  = b * RB;
  const size_t NKc = (size_t)N * K;

  // ---- A: block-invariant candidate list {j : S[j] >= tau}, index-ascending ----
  const int per = (N + THREADS - 1) / THREADS;
  const int j0 = tid * per, j1 = min(N, j0 + per);
  int c = 0;
  for (int j = j0; j < j1; ++j) c += (S[j] >= tau);
  cnts[tid] = c;
  if (tid == 0) { sNT = 0; sNU = 0; }
  __syncthreads();
  if (tid < 64) {                          // wave-0 exclusive prefix over 256 counts
    const int base = tid * 4;
    int a0 = cnts[base], a1 = cnts[base+1], a2 = cnts[base+2], a3 = cnts[base+3];
    int s = a0 + a1 + a2 + a3;
    int inc = s;
    for (int off = 1; off < 64; off <<= 1) { int o = __shfl_up(inc, off, 64); if (tid >= off) inc += o; }
    int exc = inc - s;
    cnts[base] = exc; cnts[base+1] = exc + a0;
    cnts[base+2] = exc + a0 + a1; cnts[base+3] = exc + a0 + a1 + a2;
    if (tid == 63) sT = inc;
  }
  __syncthreads();
  const int T   = sT;
  const int ovf = (T > LCAP) | (K != KF);  // unconditional-correctness escape hatch
  if (!ovf) {
    int pos = cnts[tid];
    for (int j = j0; j < j1; ++j) {
      float v = S[j];
      if (v >= tau) { listIdx[pos] = j; listVal[pos] = v; ++pos; }
    }
  }
  if (tid < RB) { rowKey[tid] = 0ull; rowSlot[tid] = -1; rowLocal[tid] = -1; }
  __syncthreads();

  // ---- B: leader assign, 16 threads/row; exact when any top-set neighbor exists ----
  const int r = tid & (RB - 1);
  const int g = tid >> 4;
  {
    const int i = i0 + r;
    if (!ovf && i < N) {
      unsigned long long lk = 0ull;
      for (int t = g; t < T; t += 16) {
        float v = J[(size_t)listIdx[t] * N + i];   // symmetric J: coalesced column read
        if (v > 0.5f) {
          unsigned long long key = ((unsigned long long)fmap(listVal[t]) << 32)
                                 | (unsigned)(0xFFFFFFFFu - (unsigned)t);
          if (key > lk) lk = key;                  // index-ascending slots: min slot == min index
        }
      }
      if (lk) atomicMax(&rowKey[r], lk);
    }
  }
  __syncthreads();
  if (tid < RB) {
    const int i = i0 + tid;
    if (i < N) {
      unsigned long long k = ovf ? 0ull : rowKey[tid];
      if (k != 0ull) {
        int slot = (int)(0xFFFFFFFFu - (unsigned)(k & 0xFFFFFFFFull));
        rowSlot[tid] = slot;
        __hip_atomic_store(&leader[i], listIdx[slot], __ATOMIC_RELAXED, __HIP_MEMORY_SCOPE_AGENT);
      } else {
        int u = atomicAdd(&sNU, 1);
        unresR[u] = tid;
      }
    }
  }
  __syncthreads();

  // ---- B': exact full-row argmax for unresolved rows (expected: none) ----
  const int nu = sNU;
  for (int u = 0; u < nu; ++u) {
    const int rr = unresR[u]; const int ii = i0 + rr;
    if (tid == 0) bkey = 0ull;
    __syncthreads();
    unsigned long long bk = 0ull;
    for (int j = tid; j < N; j += THREADS) {
      float v = J[(size_t)ii * N + j];
      if (v > 0.5f || j == ii) {
        unsigned long long key = ((unsigned long long)fmap(S[j]) << 32)
                               | (unsigned)(0xFFFFFFFFu - (unsigned)j);
        if (key > bk) bk = key;
      }
    }
    if (bk) atomicMax(&bkey, bk);
    __syncthreads();
    if (tid == 0) {
      int js = (int)(0xFFFFFFFFu - (unsigned)(bkey & 0xFFFFFFFFull));
      __hip_atomic_store(&leader[ii], js, __ATOMIC_RELAXED, __HIP_MEMORY_SCOPE_AGENT);
    }
    __syncthreads();
  }

  // ---- touch map: compact distinct slots of this block's rows (<=16) ----
  if (tid == 0) {
    int nt = 0;
    for (int rr = 0; rr < RB; ++rr) {
      int s = rowSlot[rr];
      if (s < 0) continue;
      int loc = -1;
      for (int t = 0; t < nt; ++t) if (touchSlot[t] == s) { loc = t; break; }
      if (loc < 0) { loc = nt++; touchSlot[loc] = s; touchCnt[loc] = 0; }
      touchCnt[loc]++; rowLocal[rr] = loc;
    }
    sNT = nt;
  }
  __syncthreads();
  const int nT = sNT;

  // ---- C: accumulate own rows into compact LDS slab (float4 loads) ----
  for (int idx = tid; idx < nT * K2; idx += THREADS) slab[idx] = 0.f;
  __syncthreads();
  for (int q = tid; q < RB * 40; q += THREADS) {      // 40 float4 per row (C:20|D:20)
    const int rr = q / 40, f = q - rr * 40;
    const int i = i0 + rr;
    if (i >= N) continue;
    const int loc = rowLocal[rr];
    if (loc < 0) continue;
    const float4 v = (f < 20) ? *(const float4*)(C + (size_t)i * KF + f * 4)
                              : *(const float4*)(D + (size_t)i * KF + (f - 20) * 4);
    float* sb = &slab[loc * K2 + (f < 20 ? f * 4 : KF + (f - 20) * 4)];
    atomicAdd(sb + 0, v.x); atomicAdd(sb + 1, v.y);
    atomicAdd(sb + 2, v.z); atomicAdd(sb + 3, v.w);
  }
  __syncthreads();

  // ---- D: flush counts + slab into XCD-aligned partition (b&7 ~ XCD id) ----
  if (tid < nT) atomicAdd(&slotCount[touchSlot[tid]], touchCnt[tid]);
  {
    const int p = b & (NPART - 1);
    for (int idx = tid; idx < nT * K2; idx += THREADS) {
      const int loc = idx / K2, k = idx - loc * K2;
      atomicAdd(slotPart + ((size_t)p * LCAP + touchSlot[loc]) * K2 + k, slab[idx]);
    }
  }

  // ---- grid barrier (one-shot per call; ctr/gen zeroed by memset each launch) ----
  __syncthreads();
  if (tid == 0) {
    const int nblk = gridDim.x;
    const int p = b & (NPART - 1);
    const int expect = (nblk + NPART - 1 - p) / NPART;  // blocks with b%NPART==p
    int o = atomicAdd(&subctr[p * 16], 1);
    if (o == expect - 1) {
      const int nparts = nblk < NPART ? nblk : NPART;
      int o2 = atomicAdd(master, 1);
      if (o2 == nparts - 1)
        __hip_atomic_store(gen, 1, __ATOMIC_RELEASE, __HIP_MEMORY_SCOPE_AGENT);
    }
    while (__hip_atomic_load(gen, __ATOMIC_ACQUIRE, __HIP_MEMORY_SCOPE_AGENT) == 0)
      __builtin_amdgcn_s_sleep(16);
  }
  __syncthreads();

  // ---- F: per-touched-slot means, then write own 16 output rows ----
  for (int idx = tid; idx < nT * K2; idx += THREADS) {
    const int loc = idx / K2, k = idx - loc * K2;
    const float* base = slotPart + (size_t)touchSlot[loc] * K2 + k;
    float acc = 0.f;
    #pragma unroll
    for (int pp = 0; pp < NPART; ++pp)
      acc += __hip_atomic_load(base + (size_t)pp * LCAP * K2, __ATOMIC_RELAXED, __HIP_MEMORY_SCOPE_AGENT);
    slab[idx] = acc;
  }
  if (tid < nT) {
    int cc = __hip_atomic_load(&slotCount[touchSlot[tid]], __ATOMIC_RELAXED, __HIP_MEMORY_SCOPE_AGENT);
    invCnt[tid] = 1.0f / (float)(cc > 0 ? cc : 1);
  }
  __syncthreads();
  for (int q = tid; q < RB * 40; q += THREADS) {
    const int rr = q / 40, f = q - rr * 40;
    const int i = i0 + rr;
    if (i >= N) continue;
    const int loc = rowLocal[rr];
    if (loc < 0) continue;
    const float inv = invCnt[loc];
    const float* sb = &slab[loc * K2 + (f < 20 ? f * 4 : KF + (f - 20) * 4)];
    float4 v = make_float4(sb[0] * inv, sb[1] * inv, sb[2] * inv, sb[3] * inv);
    const size_t off = (f < 20) ? ((size_t)i * KF + f * 4)
                                : (NKc + (size_t)i * KF + (f - 20) * 4);
    *(float4*)(out + off) = v;                       // contiguous rows: coalesced
  }

  // ---- F': unresolved rows — exact leader-scan mean (expected: none; any K) ----
  for (int u = 0; u < nu; ++u) {
    const int rr = unresR[u]; const int ii = i0 + rr;
    const int m = __hip_atomic_load(&leader[ii], __ATOMIC_RELAXED, __HIP_MEMORY_SCOPE_AGENT);
    for (int k = tid; k < K; k += THREADS) {
      float sc = 0.f, sd = 0.f; int cc = 0;
      for (int y = 0; y < N; ++y) {
        int ly = __hip_atomic_load(&leader[y], __ATOMIC_RELAXED, __HIP_MEMORY_SCOPE_AGENT);
        if (ly == m) { sc += C[(size_t)y * K + k]; sd += D[(size_t)y * K + k]; ++cc; }
      }
      const float inv = 1.0f / (float)(cc > 0 ? cc : 1);
      out[(size_t)ii * K + k] = sc * inv;
      out[NKc + (size_t)ii * K + k] = sd * inv;
    }
  }
}

extern "C" void kernel_launch(void* const* d_in, const int* in_sizes, int n_in,
                              void* d_out, int out_size, void* d_ws, size_t ws_size,
                              hipStream_t stream) {
  (void)n_in; (void)out_size; (void)ws_size;
  const float* S = (const float*)d_in[0];
  const float* J = (const float*)d_in[1];
  const float* C = (const float*)d_in[2];
  const float* D = (const float*)d_in[3];
  float* out = (float*)d_out;
  const int N = in_sizes[0];
  const int K = in_sizes[2] / N;

  // ws layout (zeroed prefix): slotPart[NPART][LCAP][K2] | slotCount[LCAP] | subctr[128] | master | gen || leader[N]
  float* slotPart  = (float*)d_ws;
  int*   slotCount = (int*)(slotPart + (size_t)NPART * LCAP * K2);
  int*   subctr    = slotCount + LCAP;
  int*   master    = subctr + 128;
  int*   gen       = master + 1;
  int*   leader    = gen + 1;

  const size_t zbytes = ((size_t)NPART * LCAP * K2 + LCAP + 128 + 2) * sizeof(float);
  hipMemsetAsync(d_ws, 0, zbytes, stream);

  const float tau = 1.0f - 48.0f / (float)N;   // targets E[T]=48; any tau is correct
  const int nblk = (N + RB - 1) / RB;          // 512 = 2 blocks/CU x 256 CUs (co-resident)
  mainK<<<nblk, THREADS, 0, stream>>>(S, J, C, D, tau, slotPart, slotCount,
                                      subctr, master, gen, leader, out, N, K);
}